// Round 1
// baseline (101660.132 us; speedup 1.0000x reference)
//
#include <hip/hip_runtime.h>
#include <math.h>

#define RSV   2048          // reservoir size
#define NIN   8             // input size
#define TT    16384         // time steps
#define NB    64            // persistent blocks
#define TB    512           // threads per block (8 waves)
#define RPB   (RSV/NB)      // 32 rows per block
#define CPL   128           // Wh columns held per thread
#define OUTW  (RSV+NIN)     // 2056

// ws layout (float offsets):
//   [0 .. 64)        : tags (as unsigned), one per block
//   [1024 .. 3072)   : hbuf0
//   [3072 .. 5120)   : hbuf1
// total 20 KiB

__global__ __launch_bounds__(256) void esn_init(const float* __restrict__ h0,
                                                float* __restrict__ ws) {
    int i = blockIdx.x * blockDim.x + threadIdx.x;
    if (i < NB) ((unsigned*)ws)[i] = 0u;
    if (i < RSV) ws[1024 + i] = h0[i];
}

__global__ __launch_bounds__(TB) void esn_main(const float* __restrict__ x,
                                               const float* __restrict__ h0,
                                               const float* __restrict__ Win,
                                               const float* __restrict__ Wh,
                                               float* __restrict__ out,
                                               float* __restrict__ ws) {
    __shared__ __align__(16) float h_lds[RSV];     // staged h_{t-1}
    __shared__ float part_lds[16 * 32];            // per (wave,colhalf) row partials
    __shared__ float x_lds[NIN];

    const int tid   = threadIdx.x;
    const int b     = blockIdx.x;
    const int wave  = tid >> 6;          // 0..7
    const int lane  = tid & 63;
    const int rowl  = lane & 31;         // row within block
    const int chalf = lane >> 5;         // which 128-col half of the wave's 256-col range
    const int cb    = wave * 256 + chalf * 128;   // first column this thread covers
    const int rowg  = b * RPB + rowl;             // global reservoir row

    unsigned* tags = (unsigned*)ws;
    float* hbuf0 = ws + 1024;
    float* hbuf1 = ws + 3072;

    // ---- one-time: Wh slice into registers: Wh[rowg][cb .. cb+128) ----
    float wh[CPL];
    {
        const float* wrow = Wh + (size_t)rowg * RSV + cb;
        #pragma unroll
        for (int j = 0; j < CPL / 4; ++j) {
            float4 w4 = *(const float4*)(wrow + 4 * j);
            wh[4*j+0] = w4.x; wh[4*j+1] = w4.y;
            wh[4*j+2] = w4.z; wh[4*j+3] = w4.w;
        }
    }
    // Win row (only wave 0 lanes 0..31 actually use it)
    float win[NIN];
    #pragma unroll
    for (int k = 0; k < NIN; ++k) win[k] = Win[rowg * NIN + k];

    float hp = h0[rowg];   // running leaked state for this thread's row (wave0 lanes<32)

    #pragma unroll 1
    for (int t = 1; t <= TT; ++t) {
        float* src = (t & 1) ? hbuf0 : hbuf1;   // h_{t-1}
        float* dst = (t & 1) ? hbuf1 : hbuf0;   // h_t

        // ---- poll: all 64 block tags >= t-1 (each wave polls independently;
        //      own block's tag gates LDS reuse, so no barrier needed here) ----
        {
            const unsigned tgt = (unsigned)(t - 1);
            for (;;) {
                unsigned v = __hip_atomic_load(&tags[lane], __ATOMIC_RELAXED,
                                               __HIP_MEMORY_SCOPE_AGENT);
                if (__all((int)(v >= tgt))) break;
            }
        }

        // ---- stage h_{t-1} into LDS (coherent loads -> LLC is the coherence point) ----
        {
            const int i4 = tid * 4;
            float a0 = __hip_atomic_load(src + i4 + 0, __ATOMIC_RELAXED, __HIP_MEMORY_SCOPE_AGENT);
            float a1 = __hip_atomic_load(src + i4 + 1, __ATOMIC_RELAXED, __HIP_MEMORY_SCOPE_AGENT);
            float a2 = __hip_atomic_load(src + i4 + 2, __ATOMIC_RELAXED, __HIP_MEMORY_SCOPE_AGENT);
            float a3 = __hip_atomic_load(src + i4 + 3, __ATOMIC_RELAXED, __HIP_MEMORY_SCOPE_AGENT);
            float4 hv; hv.x = a0; hv.y = a1; hv.z = a2; hv.w = a3;
            *(float4*)&h_lds[i4] = hv;
        }
        if (tid < NIN) x_lds[tid] = x[(size_t)(t - 1) * NIN + tid];
        __syncthreads();   // S2: h_lds + x_lds ready

        // ---- mat-vec partial: this thread's row over its 128 cols.
        //      All 32 lanes of a half-wave read the SAME h address -> LDS broadcast. ----
        float acc = 0.f;
        #pragma unroll
        for (int j = 0; j < CPL / 4; ++j) {
            float4 hv = *(const float4*)&h_lds[cb + 4 * j];
            acc += wh[4*j+0] * hv.x;
            acc += wh[4*j+1] * hv.y;
            acc += wh[4*j+2] * hv.z;
            acc += wh[4*j+3] * hv.w;
        }
        part_lds[(wave * 2 + chalf) * 32 + rowl] = acc;
        __syncthreads();   // S3: partials ready

        // ---- wave 0 finalizes the block's 32 rows ----
        if (wave == 0) {
            if (lane < 32) {
                float s = 0.f;
                #pragma unroll
                for (int k = 0; k < 16; ++k) s += part_lds[k * 32 + lane];
                #pragma unroll
                for (int k = 0; k < NIN; ++k) s += win[k] * x_lds[k];
                float hn = tanhf(s);
                float ht = 0.9f * hp + 0.1f * hn;
                hp = ht;
                out[(size_t)(t - 1) * OUTW + b * RPB + lane] = ht;
                __hip_atomic_store(dst + b * RPB + lane, ht, __ATOMIC_RELAXED,
                                   __HIP_MEMORY_SCOPE_AGENT);
            } else if (b == 0 && lane < 32 + NIN) {
                out[(size_t)(t - 1) * OUTW + RSV + (lane - 32)] = x_lds[lane - 32];
            }
            if (lane == 0) {
                // release: orders this wave's h-slice stores before the tag becomes visible
                __hip_atomic_store(&tags[b], (unsigned)t, __ATOMIC_RELEASE,
                                   __HIP_MEMORY_SCOPE_AGENT);
            }
        }
    }
}

extern "C" void kernel_launch(void* const* d_in, const int* in_sizes, int n_in,
                              void* d_out, int out_size, void* d_ws, size_t ws_size,
                              hipStream_t stream) {
    const float* x   = (const float*)d_in[0];
    const float* h0  = (const float*)d_in[1];
    const float* Win = (const float*)d_in[2];
    const float* Wh  = (const float*)d_in[3];
    float* out = (float*)d_out;
    float* ws  = (float*)d_ws;

    hipLaunchKernelGGL(esn_init, dim3(8), dim3(256), 0, stream, h0, ws);
    hipLaunchKernelGGL(esn_main, dim3(NB), dim3(TB), 0, stream,
                       x, h0, Win, Wh, out, ws);
}

// Round 2
// 65739.929 us; speedup vs baseline: 1.5464x; 1.5464x over previous
//
#include <hip/hip_runtime.h>
#include <math.h>

#define RSV   2048
#define NIN   8
#define TT    16384
#define NB    64
#define TB    512
#define RPB   32          // rows per block
#define RPW   4           // rows per wave
#define OUTW  (RSV+NIN)   // 2056

typedef unsigned long long u64;

// ws layout: buf0 = ws[0..2048) u64, buf1 = ws[2048..4096) u64 (32 KiB)
// word = (stamp << 32) | float_bits.  buf[p] holds h_t for t with t&1==p... (t parity)

__global__ __launch_bounds__(256) void esn_init(const float* __restrict__ h0,
                                                u64* __restrict__ ws) {
    int i = blockIdx.x * blockDim.x + threadIdx.x;
    if (i < RSV) {
        ws[i]       = (u64)__float_as_uint(h0[i]);  // buf0: stamp 0 | h0 payload
        ws[RSV + i] = 0ull;                         // buf1: stamp 0 (payload dontcare)
    }
}

__global__ __launch_bounds__(TB, 2) void esn_main(const float* __restrict__ x,
                                                  const float* __restrict__ h0,
                                                  const float* __restrict__ Win,
                                                  const float* __restrict__ Wh,
                                                  float* __restrict__ out,
                                                  u64* __restrict__ ws) {
    __shared__ __align__(16) float h_lds[RSV];
    __shared__ float x_lds[NIN];

    const int tid  = threadIdx.x;
    const int b    = blockIdx.x;
    const int wave = tid >> 6;
    const int lane = tid & 63;

    u64* buf0 = ws;
    u64* buf1 = ws + RSV;

    // ---- one-time: Wh into registers. Wave owns rows [row0,row0+4);
    //      lane owns cols {lane + 64j}. Per (r,j) the 64 lanes read 64
    //      consecutive floats -> perfectly coalesced one-time load. ----
    const int row0 = b * RPB + wave * RPW;
    float wh[RPW][32];
    #pragma unroll
    for (int r = 0; r < RPW; ++r) {
        const float* wrow = Wh + (size_t)(row0 + r) * RSV + lane;
        #pragma unroll
        for (int j = 0; j < 32; ++j) wh[r][j] = wrow[64 * j];
    }
    // finalize lanes (0..3) state: Win row + running h
    const int frow = row0 + (lane & 3);
    float win[NIN];
    #pragma unroll
    for (int k = 0; k < NIN; ++k) win[k] = Win[frow * NIN + k];
    float hp = h0[frow];

    #pragma unroll 1
    for (int t = 1; t <= TT; ++t) {
        const u64* src = (t & 1) ? buf0 : buf1;   // holds h_{t-1}
        u64*       dst = (t & 1) ? buf1 : buf0;   // receives h_t
        const unsigned want = (unsigned)(t - 1);

        // x prefetch: independent of stamps, issue before the poll
        float xv = 0.f;
        if (tid < NIN) xv = x[(size_t)(t - 1) * NIN + tid];

        // ---- poll OWN 4 stamped words (one LLC round-trip; no hot line) ----
        const u64* sp = src + tid * 4;
        u64 v0, v1, v2, v3;
        for (;;) {
            v0 = __hip_atomic_load(sp + 0, __ATOMIC_RELAXED, __HIP_MEMORY_SCOPE_AGENT);
            v1 = __hip_atomic_load(sp + 1, __ATOMIC_RELAXED, __HIP_MEMORY_SCOPE_AGENT);
            v2 = __hip_atomic_load(sp + 2, __ATOMIC_RELAXED, __HIP_MEMORY_SCOPE_AGENT);
            v3 = __hip_atomic_load(sp + 3, __ATOMIC_RELAXED, __HIP_MEMORY_SCOPE_AGENT);
            if ((unsigned)(v0 >> 32) == want && (unsigned)(v1 >> 32) == want &&
                (unsigned)(v2 >> 32) == want && (unsigned)(v3 >> 32) == want) break;
        }
        float4 hv4;
        hv4.x = __uint_as_float((unsigned)v0);
        hv4.y = __uint_as_float((unsigned)v1);
        hv4.z = __uint_as_float((unsigned)v2);
        hv4.w = __uint_as_float((unsigned)v3);
        *(float4*)&h_lds[tid * 4] = hv4;
        if (tid < NIN) x_lds[tid] = xv;
        __syncthreads();   // the ONLY barrier per step (stamps subsume the rest)

        // ---- 4-row matvec: read each h col once, FMA into 4 row accumulators.
        //      col = lane + 64j -> bank = lane%32, 2 lanes/bank = conflict-free. ----
        float4 p = {0.f, 0.f, 0.f, 0.f};
        #pragma unroll
        for (int j = 0; j < 32; ++j) {
            float hval = h_lds[lane + 64 * j];
            p.x += wh[0][j] * hval;
            p.y += wh[1][j] * hval;
            p.z += wh[2][j] * hval;
            p.w += wh[3][j] * hval;
        }
        // ---- 64-lane butterfly reduce (4 rows at once) ----
        #pragma unroll
        for (int m = 32; m >= 1; m >>= 1) {
            p.x += __shfl_xor(p.x, m);
            p.y += __shfl_xor(p.y, m);
            p.z += __shfl_xor(p.z, m);
            p.w += __shfl_xor(p.w, m);
        }

        // ---- per-wave finalize: lanes 0..3 own rows row0..row0+3 ----
        if (lane < RPW) {
            float s = (lane == 0) ? p.x : (lane == 1) ? p.y : (lane == 2) ? p.z : p.w;
            #pragma unroll
            for (int k = 0; k < NIN; ++k) s += win[k] * x_lds[k];
            float ht = 0.9f * hp + 0.1f * tanhf(s);
            hp = ht;
            const int row = row0 + lane;
            out[(size_t)(t - 1) * OUTW + row] = ht;
            u64 pk = ((u64)(unsigned)t << 32) | (u64)__float_as_uint(ht);
            __hip_atomic_store(dst + row, pk, __ATOMIC_RELAXED, __HIP_MEMORY_SCOPE_AGENT);
        } else if (b == 0 && wave == 0 && lane >= 8 && lane < 8 + NIN) {
            out[(size_t)(t - 1) * OUTW + RSV + (lane - 8)] = x_lds[lane - 8];
        }
        // no trailing barrier: a thread may only overwrite h_lds/x_lds at t+1
        // after its poll observes ALL stamps == t, and every wave stores its
        // stamp t only after its LDS reads for step t (data dependence).
    }
}

extern "C" void kernel_launch(void* const* d_in, const int* in_sizes, int n_in,
                              void* d_out, int out_size, void* d_ws, size_t ws_size,
                              hipStream_t stream) {
    const float* x   = (const float*)d_in[0];
    const float* h0  = (const float*)d_in[1];
    const float* Win = (const float*)d_in[2];
    const float* Wh  = (const float*)d_in[3];
    float* out = (float*)d_out;
    u64*   ws  = (u64*)d_ws;

    hipLaunchKernelGGL(esn_init, dim3(8), dim3(256), 0, stream, h0, ws);
    hipLaunchKernelGGL(esn_main, dim3(NB), dim3(TB), 0, stream,
                       x, h0, Win, Wh, out, ws);
}

// Round 3
// 34604.169 us; speedup vs baseline: 2.9378x; 1.8998x over previous
//
#include <hip/hip_runtime.h>
#include <math.h>

#define RSV   2048
#define NIN   8
#define TT    16384
#define NB    64
#define TB    1024
#define WPB   16          // waves per block
#define RPB   32          // rows per block
#define RPW   2           // rows per wave
#define OUTW  (RSV+NIN)   // 2056

typedef unsigned long long u64;

// ws layout: buf0 = ws[0..2048) u64, buf1 = ws[2048..4096) u64 (32 KiB)
// word = (stamp << 32) | float_bits

__global__ __launch_bounds__(256) void esn_init(const float* __restrict__ h0,
                                                u64* __restrict__ ws) {
    int i = blockIdx.x * blockDim.x + threadIdx.x;
    if (i < RSV) {
        ws[i]       = (u64)__float_as_uint(h0[i]);  // buf0: stamp 0 | h0 payload
        ws[RSV + i] = 0ull;                         // buf1: stamp 0
    }
}

__device__ __forceinline__ float tanh_fast(float s) {
    // tanh(s) = 1 - 2/(exp(2s)+1); saturates correctly at +/-inf
    return 1.0f - 2.0f / (__expf(2.0f * s) + 1.0f);
}

__global__ __launch_bounds__(TB, 4) void esn_main(const float* __restrict__ x,
                                                  const float* __restrict__ h0,
                                                  const float* __restrict__ Win,
                                                  const float* __restrict__ Wh,
                                                  float* __restrict__ out,
                                                  u64* __restrict__ ws) {
    __shared__ __align__(16) float h_lds[RSV];

    const int tid  = threadIdx.x;
    const int b    = blockIdx.x;
    const int wave = tid >> 6;
    const int lane = tid & 63;

    u64* buf0 = ws;
    u64* buf1 = ws + RSV;

    // ---- one-time: Wh into registers. Wave owns rows [row0, row0+2);
    //      lane owns cols {lane + 64j}, j=0..31. Coalesced load per (r,j). ----
    const int row0 = b * RPB + wave * RPW;
    float wh0[32], wh1[32];
    {
        const float* wr0 = Wh + (size_t)(row0 + 0) * RSV + lane;
        const float* wr1 = Wh + (size_t)(row0 + 1) * RSV + lane;
        #pragma unroll
        for (int j = 0; j < 32; ++j) wh0[j] = wr0[64 * j];
        #pragma unroll
        for (int j = 0; j < 32; ++j) wh1[j] = wr1[64 * j];
    }
    // producer lanes (lane 0,1) own one row each
    const int frow = row0 + (lane & 1);
    float win[NIN];
    #pragma unroll
    for (int k = 0; k < NIN; ++k) win[k] = Win[frow * NIN + k];
    float hp = h0[frow];

    #pragma unroll 1
    for (int t = 1; t <= TT; ++t) {
        const u64* src = (t & 1) ? buf0 : buf1;   // holds h_{t-1}
        u64*       dst = (t & 1) ? buf1 : buf0;   // receives h_t
        const unsigned want = (unsigned)(t - 1);

        // ---- h-independent work first (hides L2 latency under the poll) ----
        float winx = 0.f;
        if (lane < RPW) {
            const float4* xr = (const float4*)(x + (size_t)(t - 1) * NIN);
            float4 xa = xr[0], xb = xr[1];
            winx = win[0]*xa.x + win[1]*xa.y + win[2]*xa.z + win[3]*xa.w
                 + win[4]*xb.x + win[5]*xb.y + win[6]*xb.z + win[7]*xb.w;
        }
        if (b == 0 && tid < NIN)
            out[(size_t)(t - 1) * OUTW + RSV + tid] = x[(size_t)(t - 1) * NIN + tid];

        // ---- poll OWN 2 stamped words; block collectively covers all 2048 ----
        const u64* sp = src + tid * 2;
        u64 v0, v1;
        for (;;) {
            v0 = __hip_atomic_load(sp + 0, __ATOMIC_RELAXED, __HIP_MEMORY_SCOPE_AGENT);
            v1 = __hip_atomic_load(sp + 1, __ATOMIC_RELAXED, __HIP_MEMORY_SCOPE_AGENT);
            if ((unsigned)(v0 >> 32) == want && (unsigned)(v1 >> 32) == want) break;
        }
        float2 hv2;
        hv2.x = __uint_as_float((unsigned)v0);
        hv2.y = __uint_as_float((unsigned)v1);
        *(float2*)&h_lds[tid * 2] = hv2;
        __syncthreads();   // bar1: h_lds fully staged; also gates producer stores

        // ---- 2-row matvec: col = lane + 64j -> conflict-free LDS broadcast-free reads ----
        float px = 0.f, py = 0.f;
        #pragma unroll
        for (int j = 0; j < 32; ++j) {
            float hval = h_lds[lane + 64 * j];
            px += wh0[j] * hval;
            py += wh1[j] * hval;
        }
        __syncthreads();   // bar2: all LDS reads done -> t+1 restaging is WAR-safe

        // ---- 64-lane butterfly reduce (both rows) ----
        #pragma unroll
        for (int m = 32; m >= 1; m >>= 1) {
            px += __shfl_xor(px, m);
            py += __shfl_xor(py, m);
        }

        // ---- producer lanes finalize their row ----
        if (lane < RPW) {
            float s  = ((lane == 0) ? px : py) + winx;
            float ht = 0.9f * hp + 0.1f * tanh_fast(s);
            hp = ht;
            u64 pk = ((u64)(unsigned)t << 32) | (u64)__float_as_uint(ht);
            __hip_atomic_store(dst + frow, pk, __ATOMIC_RELAXED, __HIP_MEMORY_SCOPE_AGENT);
            out[(size_t)(t - 1) * OUTW + frow] = ht;
        }
    }
}

extern "C" void kernel_launch(void* const* d_in, const int* in_sizes, int n_in,
                              void* d_out, int out_size, void* d_ws, size_t ws_size,
                              hipStream_t stream) {
    const float* x   = (const float*)d_in[0];
    const float* h0  = (const float*)d_in[1];
    const float* Win = (const float*)d_in[2];
    const float* Wh  = (const float*)d_in[3];
    float* out = (float*)d_out;
    u64*   ws  = (u64*)d_ws;

    hipLaunchKernelGGL(esn_init, dim3(8), dim3(256), 0, stream, h0, ws);
    hipLaunchKernelGGL(esn_main, dim3(NB), dim3(TB), 0, stream,
                       x, h0, Win, Wh, out, ws);
}